// Round 1
// baseline (1902.489 us; speedup 1.0000x reference)
//
#include <hip/hip_runtime.h>

// Problem constants
constexpr int NN  = 131072;   // nodes
constexpr int NE  = 2097152;  // edges
constexpr int HD  = 128;      // hidden
constexpr int NG  = 8192;     // graphs
constexpr int NA  = 28;       // atom types
constexpr int NL  = 4;        // layers
constexpr int AS  = 260;      // LDS A-tile row stride (padded, 16B-aligned, bank-spread)

// ---------------- workspace layout (bytes) ----------------
constexpr size_t SZ_FEAT = (size_t)NN * HD * 4;          // 64 MiB
constexpr size_t OFF_X    = 0;
constexpr size_t OFF_Y    = OFF_X + SZ_FEAT;
constexpr size_t OFF_ESRC = OFF_Y + SZ_FEAT;
constexpr size_t OFF_DEG  = OFF_ESRC + (size_t)NE * 4;
constexpr size_t OFF_GCNT = OFF_DEG + (size_t)NN * 4;    // adjacent to DEG: single memset
constexpr size_t OFF_ROW  = OFF_GCNT + (size_t)NG * 4;
constexpr size_t OFF_CUR  = OFF_ROW + (size_t)NN * 4;
constexpr size_t OFF_IDEG = OFF_CUR + (size_t)NN * 4;
constexpr size_t OFF_IGC  = OFF_IDEG + (size_t)NN * 4;
constexpr size_t OFF_BSUM = OFF_IGC + (size_t)NG * 4;
constexpr size_t OFF_COFF = OFF_BSUM + 512;
constexpr size_t OFF_WC   = OFF_COFF + 512;

// ---------------- CSR build ----------------
__global__ void k_hist(const int* __restrict__ dst, const int* __restrict__ gid,
                       int* __restrict__ deg, int* __restrict__ gcnt) {
  int i = blockIdx.x * blockDim.x + threadIdx.x;
  if (i < NE) atomicAdd(&deg[dst[i]], 1);
  if (i < NN) atomicAdd(&gcnt[gid[i]], 1);
}

__global__ void k_scan1(const int* __restrict__ deg, int* __restrict__ bsum) {
  __shared__ int s[256];
  int b = blockIdx.x, t = threadIdx.x;
  const int4* p = (const int4*)(deg + (size_t)b * 1024);
  int4 v = p[t];
  s[t] = v.x + v.y + v.z + v.w;
  __syncthreads();
  for (int o = 128; o > 0; o >>= 1) {
    if (t < o) s[t] += s[t + o];
    __syncthreads();
  }
  if (t == 0) bsum[b] = s[0];
}

__global__ void k_scan2(const int* __restrict__ bsum, int* __restrict__ coff) {
  __shared__ int s[128];
  int t = threadIdx.x;
  int mine = bsum[t];
  s[t] = mine;
  __syncthreads();
  for (int o = 1; o < 128; o <<= 1) {
    int v = (t >= o) ? s[t - o] : 0;
    __syncthreads();
    s[t] += v;
    __syncthreads();
  }
  coff[t] = s[t] - mine;  // exclusive
}

__global__ void k_scan3(const int* __restrict__ deg, const int* __restrict__ coff,
                        int* __restrict__ row_start, int* __restrict__ cursor,
                        float* __restrict__ inv_deg) {
  __shared__ int s[256];
  int b = blockIdx.x, t = threadIdx.x;
  int base = b * 1024 + t * 4;
  const int4* p = (const int4*)(deg + base);
  int4 d = *p;
  int lsum = d.x + d.y + d.z + d.w;
  s[t] = lsum;
  __syncthreads();
  for (int o = 1; o < 256; o <<= 1) {
    int v = (t >= o) ? s[t - o] : 0;
    __syncthreads();
    s[t] += v;
    __syncthreads();
  }
  int pre = coff[b] + s[t] - lsum;
  int r0 = pre, r1 = r0 + d.x, r2 = r1 + d.y, r3 = r2 + d.z;
  row_start[base] = r0;  row_start[base + 1] = r1;
  row_start[base + 2] = r2;  row_start[base + 3] = r3;
  cursor[base] = r0;  cursor[base + 1] = r1;
  cursor[base + 2] = r2;  cursor[base + 3] = r3;
  inv_deg[base]     = 1.0f / fmaxf((float)d.x, 1.0f);
  inv_deg[base + 1] = 1.0f / fmaxf((float)d.y, 1.0f);
  inv_deg[base + 2] = 1.0f / fmaxf((float)d.z, 1.0f);
  inv_deg[base + 3] = 1.0f / fmaxf((float)d.w, 1.0f);
}

__global__ void k_place(const int* __restrict__ src, const int* __restrict__ dst,
                        int* __restrict__ cursor, int* __restrict__ esrc) {
  int e = blockIdx.x * blockDim.x + threadIdx.x;
  if (e < NE) {
    int p = atomicAdd(&cursor[dst[e]], 1);
    esrc[p] = src[e];
  }
}

__global__ void k_ginit(const int* __restrict__ gcnt, float* __restrict__ inv_gcnt,
                        float* __restrict__ out, const float* __restrict__ b_pred) {
  int g = blockIdx.x * blockDim.x + threadIdx.x;
  if (g < NG) {
    inv_gcnt[g] = 1.0f / fmaxf((float)gcnt[g], 1.0f);
    out[g] = b_pred[0];
  }
}

// ---------------- embedding: X = h @ W_emb  [N,28]x[28,128] ----------------
__global__ void k_embed(const float* __restrict__ h, const float* __restrict__ W,
                        float* __restrict__ X) {
  __shared__ float w[NA * HD];
  int t = threadIdx.x;
  for (int i = t; i < NA * HD; i += 256) w[i] = W[i];
  __syncthreads();
  int col = t & 127, rh = t >> 7;
  int row0 = blockIdx.x * 16;
  for (int r = rh; r < 16; r += 2) {
    int row = row0 + r;
    const float* hr = h + (size_t)row * NA;
    float acc = 0.f;
#pragma unroll
    for (int k = 0; k < NA; k++) acc += hr[k] * w[k * HD + col];
    X[(size_t)row * HD + col] = acc;
  }
}

// ---------------- aggregation: C[v] = mean_{u->v} H[u] ----------------
__global__ void k_agg(const float* __restrict__ H, const int* __restrict__ row_start,
                      const int* __restrict__ deg, const int* __restrict__ esrc,
                      const float* __restrict__ inv_deg, float* __restrict__ C) {
  int v = blockIdx.x * 2 + (threadIdx.x >> 7);
  int t = threadIdx.x & 127;
  int rs = row_start[v], d = deg[v];
  float acc = 0.f;
  if (d > 0) {
    int s = esrc[rs];
    for (int e = 0; e < d - 1; e++) {
      int sn = esrc[rs + e + 1];           // prefetch next index
      acc += H[(size_t)s * HD + t];
      s = sn;
    }
    acc += H[(size_t)s * HD + t];
  }
  C[(size_t)v * HD + t] = acc * inv_deg[v];
}

// ---------------- NodeApply: Cio <- relu([H||Cio] @ W + b)*snorm + H ----------------
__global__ __launch_bounds__(256) void k_apply(const float* __restrict__ Hin,
                                               float* __restrict__ Cio,
                                               const float* __restrict__ W,
                                               const float* __restrict__ bias,
                                               const float* __restrict__ snorm) {
  __shared__ float As[64 * AS];        // 64 rows x 256 cols (padded stride 260)
  __shared__ float Ws[16 * HD];        // one 16x128 W tile
  int t = threadIdx.x;
  int row0 = blockIdx.x * 64;

  // Load full A tile: cols 0..127 = Hin row, 128..255 = Cio row (float4 chunks)
  for (int i = t; i < 64 * 64; i += 256) {
    int r = i >> 6, c4 = i & 63;
    const float* srcp = (c4 < 32) ? (Hin + ((size_t)(row0 + r)) * HD + c4 * 4)
                                  : (Cio + ((size_t)(row0 + r)) * HD + (c4 - 32) * 4);
    float4 v = *(const float4*)srcp;
    float* dstp = As + r * AS + c4 * 4;
    dstp[0] = v.x; dstp[1] = v.y; dstp[2] = v.z; dstp[3] = v.w;
  }

  float acc[8][4] = {};
  int tx = t & 31, ty = t >> 5;        // cols tx*4..+3, rows ty*8..+7

  for (int kt = 0; kt < 16; kt++) {
    // stage W tile 16x128
    const float* wsrc = W + (size_t)kt * 16 * HD;
    for (int i = t; i < 512; i += 256) {
      *(float4*)(Ws + i * 4) = *(const float4*)(wsrc + i * 4);
    }
    __syncthreads();
#pragma unroll
    for (int k4 = 0; k4 < 4; k4++) {
      float av[8][4];
#pragma unroll
      for (int r = 0; r < 8; r++)
        *(float4*)&av[r][0] = *(const float4*)(As + (ty * 8 + r) * AS + kt * 16 + k4 * 4);
#pragma unroll
      for (int kk = 0; kk < 4; kk++) {
        float wv[4];
        *(float4*)wv = *(const float4*)(Ws + (k4 * 4 + kk) * HD + tx * 4);
#pragma unroll
        for (int r = 0; r < 8; r++) {
          acc[r][0] += av[r][kk] * wv[0];
          acc[r][1] += av[r][kk] * wv[1];
          acc[r][2] += av[r][kk] * wv[2];
          acc[r][3] += av[r][kk] * wv[3];
        }
      }
    }
    __syncthreads();
  }

  // epilogue: relu(+bias)*snorm + residual, in-place into Cio
  int col = tx * 4;
  float4 bv = *(const float4*)(bias + col);
#pragma unroll
  for (int r = 0; r < 8; r++) {
    int row = row0 + ty * 8 + r;
    float sn = snorm[row];
    float4 hv = *(const float4*)(Hin + (size_t)row * HD + col);
    float4 o;
    o.x = fmaxf(acc[r][0] + bv.x, 0.f) * sn + hv.x;
    o.y = fmaxf(acc[r][1] + bv.y, 0.f) * sn + hv.y;
    o.z = fmaxf(acc[r][2] + bv.z, 0.f) * sn + hv.z;
    o.w = fmaxf(acc[r][3] + bv.w, 0.f) * sn + hv.w;
    *(float4*)(Cio + (size_t)row * HD + col) = o;
  }
}

// ---------------- readout ----------------
__global__ void k_wcombo(const float* __restrict__ W_ro, const float* __restrict__ W_pred,
                         float* __restrict__ wc) {
  int i = threadIdx.x;  // 128
  float a = 0.f;
  for (int j = 0; j < HD; j++) a += W_ro[i * HD + j] * W_pred[j];
  wc[i] = a;
}

__global__ void k_readout(const float* __restrict__ H, const float* __restrict__ wc,
                          const int* __restrict__ gid, const float* __restrict__ inv_gcnt,
                          float* __restrict__ out) {
  int wave = threadIdx.x >> 6, lane = threadIdx.x & 63;
  int v = blockIdx.x * 4 + wave;
  float2 hv = *(const float2*)(H + (size_t)v * HD + lane * 2);
  float2 wv = *(const float2*)(wc + lane * 2);
  float p = hv.x * wv.x + hv.y * wv.y;
#pragma unroll
  for (int o = 32; o > 0; o >>= 1) p += __shfl_down(p, o, 64);
  if (lane == 0) {
    int g = gid[v];
    atomicAdd(&out[g], p * inv_gcnt[g]);
  }
}

// ---------------- launch ----------------
extern "C" void kernel_launch(void* const* d_in, const int* in_sizes, int n_in,
                              void* d_out, int out_size, void* d_ws, size_t ws_size,
                              hipStream_t stream) {
  const float* h      = (const float*)d_in[0];
  const float* snorm  = (const float*)d_in[1];
  const float* W_emb  = (const float*)d_in[2];
  const float* W_node = (const float*)d_in[3];
  const float* b_node = (const float*)d_in[4];
  const float* W_ro   = (const float*)d_in[5];
  const float* W_pred = (const float*)d_in[6];
  const float* b_pred = (const float*)d_in[7];
  const int*   src    = (const int*)d_in[8];
  const int*   dst    = (const int*)d_in[9];
  const int*   gid    = (const int*)d_in[10];
  float* out = (float*)d_out;

  char* ws = (char*)d_ws;
  float* X        = (float*)(ws + OFF_X);
  float* Y        = (float*)(ws + OFF_Y);
  int*   esrc     = (int*)(ws + OFF_ESRC);
  int*   deg      = (int*)(ws + OFF_DEG);
  int*   gcnt     = (int*)(ws + OFF_GCNT);
  int*   row_s    = (int*)(ws + OFF_ROW);
  int*   cursor   = (int*)(ws + OFF_CUR);
  float* inv_deg  = (float*)(ws + OFF_IDEG);
  float* inv_gcnt = (float*)(ws + OFF_IGC);
  int*   bsum     = (int*)(ws + OFF_BSUM);
  int*   coff     = (int*)(ws + OFF_COFF);
  float* wc       = (float*)(ws + OFF_WC);

  // zero deg + gcnt (adjacent)
  hipMemsetAsync(ws + OFF_DEG, 0, (size_t)(NN + NG) * 4, stream);

  k_hist<<<NE / 256, 256, 0, stream>>>(dst, gid, deg, gcnt);
  k_scan1<<<NN / 1024, 256, 0, stream>>>(deg, bsum);
  k_scan2<<<1, 128, 0, stream>>>(bsum, coff);
  k_scan3<<<NN / 1024, 256, 0, stream>>>(deg, coff, row_s, cursor, inv_deg);
  k_place<<<NE / 256, 256, 0, stream>>>(src, dst, cursor, esrc);
  k_ginit<<<NG / 256, 256, 0, stream>>>(gcnt, inv_gcnt, out, b_pred);

  k_embed<<<NN / 16, 256, 0, stream>>>(h, W_emb, X);

  for (int l = 0; l < NL; l++) {
    float* hb = (l & 1) ? Y : X;
    float* cb = (l & 1) ? X : Y;
    k_agg<<<NN / 2, 256, 0, stream>>>(hb, row_s, deg, esrc, inv_deg, cb);
    k_apply<<<NN / 64, 256, 0, stream>>>(hb, cb,
                                         W_node + (size_t)l * 2 * HD * HD,
                                         b_node + (size_t)l * HD, snorm);
  }
  // final h is in X after 4 layers (X->Y->X->Y->X)

  k_wcombo<<<1, 128, 0, stream>>>(W_ro, W_pred, wc);
  k_readout<<<NN / 4, 256, 0, stream>>>(X, wc, gid, inv_gcnt, out);
}

// Round 2
// 958.029 us; speedup vs baseline: 1.9858x; 1.9858x over previous
//
#include <hip/hip_runtime.h>

// Problem constants
constexpr int NN  = 131072;   // nodes
constexpr int NE  = 2097152;  // edges
constexpr int HD  = 128;      // hidden
constexpr int NG  = 8192;     // graphs
constexpr int NA  = 28;       // atom types
constexpr int NL  = 4;        // layers

// ---------------- workspace layout (bytes) ----------------
constexpr size_t SZ_FB  = (size_t)NN * HD * 2;           // 32 MiB bf16 feature buf
constexpr size_t OFF_XB   = 0;
constexpr size_t OFF_YB   = OFF_XB + SZ_FB;
constexpr size_t OFF_ESRC = OFF_YB + SZ_FB;
constexpr size_t OFF_DEG  = OFF_ESRC + (size_t)NE * 4;
constexpr size_t OFF_GCNT = OFF_DEG + (size_t)NN * 4;    // adjacent to DEG: single memset
constexpr size_t OFF_ROW  = OFF_GCNT + (size_t)NG * 4;
constexpr size_t OFF_CUR  = OFF_ROW + (size_t)NN * 4;
constexpr size_t OFF_IDEG = OFF_CUR + (size_t)NN * 4;
constexpr size_t OFF_IGC  = OFF_IDEG + (size_t)NN * 4;
constexpr size_t OFF_BSUM = OFF_IGC + (size_t)NG * 4;
constexpr size_t OFF_COFF = OFF_BSUM + 512;
constexpr size_t OFF_WC   = OFF_COFF + 512;
constexpr size_t OFF_WNT  = OFF_WC + 512;                // bf16 W transposed [L][128][256]

// ---------------- bf16 helpers ----------------
__device__ __forceinline__ float blo(uint x) { return __uint_as_float(x << 16); }
__device__ __forceinline__ float bhi(uint x) { return __uint_as_float(x & 0xFFFF0000u); }
__device__ __forceinline__ unsigned short f2b(float f) {
  uint u = __float_as_uint(f);
  return (unsigned short)((u + 0x7FFFu + ((u >> 16) & 1u)) >> 16);
}
__device__ __forceinline__ uint pack2(float a, float b) {
  uint ua = __float_as_uint(a), ub = __float_as_uint(b);
  uint lo = (ua + 0x7FFFu + ((ua >> 16) & 1u)) >> 16;
  uint hi = (ub + 0x7FFFu + ((ub >> 16) & 1u)) & 0xFFFF0000u;
  return lo | hi;
}

typedef __attribute__((ext_vector_type(8))) short bf16x8;
typedef __attribute__((ext_vector_type(4))) float f32x4;

// ---------------- CSR build ----------------
__global__ void k_hist(const int* __restrict__ dst, const int* __restrict__ gid,
                       int* __restrict__ deg, int* __restrict__ gcnt) {
  int i = blockIdx.x * blockDim.x + threadIdx.x;
  if (i < NE) atomicAdd(&deg[dst[i]], 1);
  if (i < NN) atomicAdd(&gcnt[gid[i]], 1);
}

__global__ void k_scan1(const int* __restrict__ deg, int* __restrict__ bsum) {
  __shared__ int s[256];
  int b = blockIdx.x, t = threadIdx.x;
  const int4* p = (const int4*)(deg + (size_t)b * 1024);
  int4 v = p[t];
  s[t] = v.x + v.y + v.z + v.w;
  __syncthreads();
  for (int o = 128; o > 0; o >>= 1) {
    if (t < o) s[t] += s[t + o];
    __syncthreads();
  }
  if (t == 0) bsum[b] = s[0];
}

__global__ void k_scan2(const int* __restrict__ bsum, int* __restrict__ coff) {
  __shared__ int s[128];
  int t = threadIdx.x;
  int mine = bsum[t];
  s[t] = mine;
  __syncthreads();
  for (int o = 1; o < 128; o <<= 1) {
    int v = (t >= o) ? s[t - o] : 0;
    __syncthreads();
    s[t] += v;
    __syncthreads();
  }
  coff[t] = s[t] - mine;  // exclusive
}

__global__ void k_scan3(const int* __restrict__ deg, const int* __restrict__ coff,
                        int* __restrict__ row_start, int* __restrict__ cursor,
                        float* __restrict__ inv_deg) {
  __shared__ int s[256];
  int b = blockIdx.x, t = threadIdx.x;
  int base = b * 1024 + t * 4;
  const int4* p = (const int4*)(deg + base);
  int4 d = *p;
  int lsum = d.x + d.y + d.z + d.w;
  s[t] = lsum;
  __syncthreads();
  for (int o = 1; o < 256; o <<= 1) {
    int v = (t >= o) ? s[t - o] : 0;
    __syncthreads();
    s[t] += v;
    __syncthreads();
  }
  int pre = coff[b] + s[t] - lsum;
  int r0 = pre, r1 = r0 + d.x, r2 = r1 + d.y, r3 = r2 + d.z;
  row_start[base] = r0;  row_start[base + 1] = r1;
  row_start[base + 2] = r2;  row_start[base + 3] = r3;
  cursor[base] = r0;  cursor[base + 1] = r1;
  cursor[base + 2] = r2;  cursor[base + 3] = r3;
  inv_deg[base]     = 1.0f / fmaxf((float)d.x, 1.0f);
  inv_deg[base + 1] = 1.0f / fmaxf((float)d.y, 1.0f);
  inv_deg[base + 2] = 1.0f / fmaxf((float)d.z, 1.0f);
  inv_deg[base + 3] = 1.0f / fmaxf((float)d.w, 1.0f);
}

__global__ void k_place(const int* __restrict__ src, const int* __restrict__ dst,
                        int* __restrict__ cursor, int* __restrict__ esrc) {
  int e = blockIdx.x * blockDim.x + threadIdx.x;
  if (e < NE) {
    int p = atomicAdd(&cursor[dst[e]], 1);
    esrc[p] = src[e];
  }
}

__global__ void k_ginit(const int* __restrict__ gcnt, float* __restrict__ inv_gcnt,
                        float* __restrict__ out, const float* __restrict__ b_pred) {
  int g = blockIdx.x * blockDim.x + threadIdx.x;
  if (g < NG) {
    inv_gcnt[g] = 1.0f / fmaxf((float)gcnt[g], 1.0f);
    out[g] = b_pred[0];
  }
}

// ---------------- weight prep: Wnt[l][c][k] = bf16(W_node[l][k][c]) ----------------
__global__ void k_wprep(const float* __restrict__ Wn, unsigned short* __restrict__ Wnt) {
  int i = blockIdx.x * 256 + threadIdx.x;   // L*256*128 total
  int l = i >> 15;
  int k = (i >> 7) & 255;
  int c = i & 127;
  float v = Wn[((size_t)l * 256 + k) * HD + c];
  Wnt[((size_t)l * HD + c) * 256 + k] = f2b(v);
}

// ---------------- embedding: Xb = bf16(h @ W_emb)  [N,28]x[28,128] ----------------
__global__ void k_embed(const float* __restrict__ h, const float* __restrict__ W,
                        unsigned short* __restrict__ Xb) {
  __shared__ float w[NA * HD];
  int t = threadIdx.x;
  for (int i = t; i < NA * HD; i += 256) w[i] = W[i];
  __syncthreads();
  int col = t & 127, rh = t >> 7;
  int row0 = blockIdx.x * 16;
  for (int r = rh; r < 16; r += 2) {
    int row = row0 + r;
    const float* hr = h + (size_t)row * NA;
    float acc = 0.f;
#pragma unroll
    for (int k = 0; k < NA; k++) acc += hr[k] * w[k * HD + col];
    Xb[(size_t)row * HD + col] = f2b(acc);
  }
}

// ---------------- aggregation: Cb[v] = bf16(mean_{u->v} Hb[u]) ----------------
// one wave per node; lane holds 2 bf16 columns; 4 edges in flight
__global__ __launch_bounds__(256) void k_agg(const uint* __restrict__ H32,
                      const int* __restrict__ row_start, const int* __restrict__ deg,
                      const int* __restrict__ esrc, const float* __restrict__ inv_deg,
                      uint* __restrict__ C32) {
  int v = blockIdx.x * 4 + (threadIdx.x >> 6);
  int lane = threadIdx.x & 63;
  int rs = __builtin_amdgcn_readfirstlane(row_start[v]);
  int d  = __builtin_amdgcn_readfirstlane(deg[v]);
  float s0 = 0.f, s1 = 0.f, t0 = 0.f, t1 = 0.f;
  float u0 = 0.f, u1 = 0.f, w0 = 0.f, w1 = 0.f;
  int e = 0;
  for (; e + 4 <= d; e += 4) {
    int i0 = esrc[rs + e];
    int i1 = esrc[rs + e + 1];
    int i2 = esrc[rs + e + 2];
    int i3 = esrc[rs + e + 3];
    uint x0 = H32[(size_t)i0 * 64 + lane];
    uint x1 = H32[(size_t)i1 * 64 + lane];
    uint x2 = H32[(size_t)i2 * 64 + lane];
    uint x3 = H32[(size_t)i3 * 64 + lane];
    s0 += blo(x0); s1 += bhi(x0);
    t0 += blo(x1); t1 += bhi(x1);
    u0 += blo(x2); u1 += bhi(x2);
    w0 += blo(x3); w1 += bhi(x3);
  }
  for (; e < d; e++) {
    uint x = H32[(size_t)esrc[rs + e] * 64 + lane];
    s0 += blo(x); s1 += bhi(x);
  }
  float id = inv_deg[v];
  float c0 = ((s0 + t0) + (u0 + w0)) * id;
  float c1 = ((s1 + t1) + (u1 + w1)) * id;
  C32[(size_t)v * 64 + lane] = pack2(c0, c1);
}

// ---------------- NodeApply (MFMA): Cio <- bf16(relu([Hb||Cio]@W + b)*snorm + Hb) ----
// block: 64 rows x 128 cols, 4 waves in 2x2; no LDS (A from global rows, B from Wt)
__global__ __launch_bounds__(256) void k_apply(const unsigned short* __restrict__ Hb,
                                               unsigned short* __restrict__ Cio,
                                               const unsigned short* __restrict__ Wt,
                                               const float* __restrict__ bias,
                                               const float* __restrict__ snorm) {
  int t = threadIdx.x;
  int lane = t & 63, w = t >> 6;
  int wr = w >> 1, wc = w & 1;
  int row0 = blockIdx.x * 64 + wr * 32;
  int col0 = wc * 64;
  int fr = lane & 15;           // A-row / B-col within tile
  int fk = (lane >> 4) * 8;     // k sub-offset

  f32x4 acc[2][4] = {};

#pragma unroll
  for (int ks = 0; ks < 8; ks++) {
    int kb = ks * 32 + fk;      // 0..255 in 8-elem chunks
    bf16x8 a[2];
#pragma unroll
    for (int rt = 0; rt < 2; rt++) {
      int row = row0 + rt * 16 + fr;
      const unsigned short* ap = (kb < HD)
          ? (Hb  + (size_t)row * HD + kb)
          : (Cio + (size_t)row * HD + (kb - HD));
      a[rt] = *(const bf16x8*)ap;
    }
#pragma unroll
    for (int ct = 0; ct < 4; ct++) {
      int col = col0 + ct * 16 + fr;
      bf16x8 b = *(const bf16x8*)(Wt + (size_t)col * 256 + ks * 32 + fk);
#pragma unroll
      for (int rt = 0; rt < 2; rt++)
        acc[rt][ct] = __builtin_amdgcn_mfma_f32_16x16x32_bf16(a[rt], b, acc[rt][ct], 0, 0, 0);
    }
  }

  __syncthreads();   // all reads of Cio in this block done before in-place writes

  int oc = lane & 15;
  int orb = (lane >> 4) * 4;
#pragma unroll
  for (int rt = 0; rt < 2; rt++) {
#pragma unroll
    for (int ct = 0; ct < 4; ct++) {
      int col = col0 + ct * 16 + oc;
      float bv = bias[col];
#pragma unroll
      for (int r = 0; r < 4; r++) {
        int row = row0 + rt * 16 + orb + r;
        float sn = snorm[row];
        float hres = __uint_as_float(((uint)Hb[(size_t)row * HD + col]) << 16);
        float o = fmaxf(acc[rt][ct][r] + bv, 0.f) * sn + hres;
        Cio[(size_t)row * HD + col] = f2b(o);
      }
    }
  }
}

// ---------------- readout ----------------
__global__ void k_wcombo(const float* __restrict__ W_ro, const float* __restrict__ W_pred,
                         float* __restrict__ wcv) {
  int i = threadIdx.x;  // 128
  float a = 0.f;
  for (int j = 0; j < HD; j++) a += W_ro[i * HD + j] * W_pred[j];
  wcv[i] = a;
}

__global__ void k_readout(const uint* __restrict__ H32, const float* __restrict__ wcv,
                          const int* __restrict__ gid, const float* __restrict__ inv_gcnt,
                          float* __restrict__ out) {
  int wave = threadIdx.x >> 6, lane = threadIdx.x & 63;
  int v = blockIdx.x * 4 + wave;
  uint x = H32[(size_t)v * 64 + lane];
  float2 wv = *(const float2*)(wcv + lane * 2);
  float p = blo(x) * wv.x + bhi(x) * wv.y;
#pragma unroll
  for (int o = 32; o > 0; o >>= 1) p += __shfl_down(p, o, 64);
  if (lane == 0) {
    int g = gid[v];
    atomicAdd(&out[g], p * inv_gcnt[g]);
  }
}

// ---------------- launch ----------------
extern "C" void kernel_launch(void* const* d_in, const int* in_sizes, int n_in,
                              void* d_out, int out_size, void* d_ws, size_t ws_size,
                              hipStream_t stream) {
  const float* h      = (const float*)d_in[0];
  const float* snorm  = (const float*)d_in[1];
  const float* W_emb  = (const float*)d_in[2];
  const float* W_node = (const float*)d_in[3];
  const float* b_node = (const float*)d_in[4];
  const float* W_ro   = (const float*)d_in[5];
  const float* W_pred = (const float*)d_in[6];
  const float* b_pred = (const float*)d_in[7];
  const int*   src    = (const int*)d_in[8];
  const int*   dst    = (const int*)d_in[9];
  const int*   gid    = (const int*)d_in[10];
  float* out = (float*)d_out;

  char* ws = (char*)d_ws;
  unsigned short* Xb   = (unsigned short*)(ws + OFF_XB);
  unsigned short* Yb   = (unsigned short*)(ws + OFF_YB);
  int*   esrc     = (int*)(ws + OFF_ESRC);
  int*   deg      = (int*)(ws + OFF_DEG);
  int*   gcnt     = (int*)(ws + OFF_GCNT);
  int*   row_s    = (int*)(ws + OFF_ROW);
  int*   cursor   = (int*)(ws + OFF_CUR);
  float* inv_deg  = (float*)(ws + OFF_IDEG);
  float* inv_gcnt = (float*)(ws + OFF_IGC);
  int*   bsum     = (int*)(ws + OFF_BSUM);
  int*   coff     = (int*)(ws + OFF_COFF);
  float* wcv      = (float*)(ws + OFF_WC);
  unsigned short* Wnt = (unsigned short*)(ws + OFF_WNT);

  hipMemsetAsync(ws + OFF_DEG, 0, (size_t)(NN + NG) * 4, stream);

  k_hist<<<NE / 256, 256, 0, stream>>>(dst, gid, deg, gcnt);
  k_scan1<<<NN / 1024, 256, 0, stream>>>(deg, bsum);
  k_scan2<<<1, 128, 0, stream>>>(bsum, coff);
  k_scan3<<<NN / 1024, 256, 0, stream>>>(deg, coff, row_s, cursor, inv_deg);
  k_place<<<NE / 256, 256, 0, stream>>>(src, dst, cursor, esrc);
  k_ginit<<<NG / 256, 256, 0, stream>>>(gcnt, inv_gcnt, out, b_pred);
  k_wprep<<<(NL * 256 * HD) / 256, 256, 0, stream>>>(W_node, Wnt);

  k_embed<<<NN / 16, 256, 0, stream>>>(h, W_emb, Xb);

  for (int l = 0; l < NL; l++) {
    unsigned short* hb = (l & 1) ? Yb : Xb;
    unsigned short* cb = (l & 1) ? Xb : Yb;
    k_agg<<<NN / 4, 256, 0, stream>>>((const uint*)hb, row_s, deg, esrc, inv_deg,
                                      (uint*)cb);
    k_apply<<<NN / 64, 256, 0, stream>>>(hb, cb, Wnt + (size_t)l * HD * 256,
                                         b_node + (size_t)l * HD, snorm);
  }
  // final h is in Xb after 4 layers

  k_wcombo<<<1, 128, 0, stream>>>(W_ro, W_pred, wcv);
  k_readout<<<NN / 4, 256, 0, stream>>>((const uint*)Xb, wcv, gid, inv_gcnt, out);
}

// Round 3
// 755.094 us; speedup vs baseline: 2.5195x; 1.2688x over previous
//
#include <hip/hip_runtime.h>

// Problem constants
constexpr int NN  = 131072;   // nodes
constexpr int NE  = 2097152;  // edges
constexpr int HD  = 128;      // hidden
constexpr int NG  = 8192;     // graphs
constexpr int NA  = 28;       // atom types
constexpr int NL  = 4;        // layers

// CSR bucketing
constexpr int NB   = 256;     // buckets
constexpr int BSH  = 9;       // dst>>9 -> bucket (512 nodes/bucket)
constexpr int BNOD = 512;     // nodes per bucket
constexpr int CAP  = 10240;   // slots per bucket (mean 8192 + 22 sigma)

// ---------------- workspace layout (bytes) ----------------
constexpr size_t SZ_FB   = (size_t)NN * HD * 2;          // 32 MiB bf16 feature buf
constexpr size_t OFF_XB   = 0;
constexpr size_t OFF_YB   = OFF_XB + SZ_FB;
constexpr size_t OFF_ESRC = OFF_YB + SZ_FB;
constexpr size_t OFF_DEG  = OFF_ESRC + (size_t)NE * 4;
constexpr size_t OFF_GCNT = OFF_DEG + (size_t)NN * 4;
constexpr size_t OFF_ROW  = OFF_GCNT + (size_t)NG * 4;
constexpr size_t OFF_IDEG = OFF_ROW + (size_t)NN * 4;
constexpr size_t OFF_IGC  = OFF_IDEG + (size_t)NN * 4;
constexpr size_t OFF_BSUM = OFF_IGC + (size_t)NG * 4;
constexpr size_t OFF_COFF = OFF_BSUM + 512;
constexpr size_t OFF_WC   = OFF_COFF + 512;
constexpr size_t OFF_WNT  = OFF_WC + 512;                // bf16 W transposed [L][128][256]
constexpr size_t OFF_EBUF = OFF_WNT + (size_t)NL * HD * 256 * 2;
constexpr size_t OFF_GCUR = OFF_EBUF + (size_t)NB * CAP * 4;

// ---------------- bf16 helpers ----------------
__device__ __forceinline__ float blo(uint x) { return __uint_as_float(x << 16); }
__device__ __forceinline__ float bhi(uint x) { return __uint_as_float(x & 0xFFFF0000u); }
__device__ __forceinline__ unsigned short f2b(float f) {
  uint u = __float_as_uint(f);
  return (unsigned short)((u + 0x7FFFu + ((u >> 16) & 1u)) >> 16);
}
__device__ __forceinline__ uint pack2(float a, float b) {
  uint ua = __float_as_uint(a), ub = __float_as_uint(b);
  uint lo = (ua + 0x7FFFu + ((ua >> 16) & 1u)) >> 16;
  uint hi = (ub + 0x7FFFu + ((ub >> 16) & 1u)) & 0xFFFF0000u;
  return lo | hi;
}

typedef __attribute__((ext_vector_type(8))) short bf16x8;
typedef __attribute__((ext_vector_type(4))) float f32x4;

// ---------------- CSR build: bucketed ----------------
__global__ void k_binit(int* __restrict__ gcur) {
  int b = threadIdx.x;           // 256
  gcur[b] = b * CAP;
}

// partition edges into NB buckets by dst>>BSH; packed = (dst&511)<<17 | src
__global__ __launch_bounds__(256) void k_bin(const int* __restrict__ src,
                                             const int* __restrict__ dst,
                                             int* __restrict__ gcur,
                                             uint* __restrict__ ebuf) {
  __shared__ int cnt[NB];
  __shared__ int gbase[NB];
  int t = threadIdx.x;
  cnt[t] = 0;
  int es[16], ed[16];
  int base = blockIdx.x * 4096 + t;
#pragma unroll
  for (int j = 0; j < 16; j++) {
    es[j] = src[base + j * 256];
    ed[j] = dst[base + j * 256];
  }
  __syncthreads();
#pragma unroll
  for (int j = 0; j < 16; j++) atomicAdd(&cnt[ed[j] >> BSH], 1);
  __syncthreads();
  int c = cnt[t];
  if (c > 0) gbase[t] = atomicAdd(&gcur[t], c);
  cnt[t] = 0;
  __syncthreads();
#pragma unroll
  for (int j = 0; j < 16; j++) {
    int b = ed[j] >> BSH;
    int r = atomicAdd(&cnt[b], 1);
    ebuf[(size_t)gbase[b] + r] = ((uint)(ed[j] & (BNOD - 1)) << 17) | (uint)es[j];
  }
}

// per-bucket degree histogram (LDS), coalesced deg writes, no global atomics
__global__ __launch_bounds__(256) void k_deg(const int* __restrict__ gcur,
                                             const uint* __restrict__ ebuf,
                                             int* __restrict__ deg) {
  __shared__ int h[BNOD];
  int b = blockIdx.x, t = threadIdx.x;
  h[t] = 0; h[t + 256] = 0;
  int n = gcur[b] - b * CAP;
  __syncthreads();
  const uint* eb = ebuf + (size_t)b * CAP;
  for (int i = t; i < n; i += 256) atomicAdd(&h[eb[i] >> 17], 1);
  __syncthreads();
  deg[b * BNOD + t] = h[t];
  deg[b * BNOD + t + 256] = h[t + 256];
}

__global__ void k_scan1(const int* __restrict__ deg, int* __restrict__ bsum) {
  __shared__ int s[256];
  int b = blockIdx.x, t = threadIdx.x;
  const int4* p = (const int4*)(deg + (size_t)b * 1024);
  int4 v = p[t];
  s[t] = v.x + v.y + v.z + v.w;
  __syncthreads();
  for (int o = 128; o > 0; o >>= 1) {
    if (t < o) s[t] += s[t + o];
    __syncthreads();
  }
  if (t == 0) bsum[b] = s[0];
}

__global__ void k_scan2(const int* __restrict__ bsum, int* __restrict__ coff) {
  __shared__ int s[128];
  int t = threadIdx.x;
  int mine = bsum[t];
  s[t] = mine;
  __syncthreads();
  for (int o = 1; o < 128; o <<= 1) {
    int v = (t >= o) ? s[t - o] : 0;
    __syncthreads();
    s[t] += v;
    __syncthreads();
  }
  coff[t] = s[t] - mine;  // exclusive
}

__global__ void k_scan3(const int* __restrict__ deg, const int* __restrict__ coff,
                        int* __restrict__ row_start, float* __restrict__ inv_deg) {
  __shared__ int s[256];
  int b = blockIdx.x, t = threadIdx.x;
  int base = b * 1024 + t * 4;
  const int4* p = (const int4*)(deg + base);
  int4 d = *p;
  int lsum = d.x + d.y + d.z + d.w;
  s[t] = lsum;
  __syncthreads();
  for (int o = 1; o < 256; o <<= 1) {
    int v = (t >= o) ? s[t - o] : 0;
    __syncthreads();
    s[t] += v;
    __syncthreads();
  }
  int pre = coff[b] + s[t] - lsum;
  int r0 = pre, r1 = r0 + d.x, r2 = r1 + d.y, r3 = r2 + d.z;
  row_start[base] = r0;  row_start[base + 1] = r1;
  row_start[base + 2] = r2;  row_start[base + 3] = r3;
  inv_deg[base]     = 1.0f / fmaxf((float)d.x, 1.0f);
  inv_deg[base + 1] = 1.0f / fmaxf((float)d.y, 1.0f);
  inv_deg[base + 2] = 1.0f / fmaxf((float)d.z, 1.0f);
  inv_deg[base + 3] = 1.0f / fmaxf((float)d.w, 1.0f);
}

// per-bucket placement: LDS cursors, esrc writes land in a 32KB window
__global__ __launch_bounds__(256) void k_place2(const int* __restrict__ gcur,
                                                const uint* __restrict__ ebuf,
                                                const int* __restrict__ row_start,
                                                int* __restrict__ esrc) {
  __shared__ int cur[BNOD];
  int b = blockIdx.x, t = threadIdx.x;
  cur[t] = row_start[b * BNOD + t];
  cur[t + 256] = row_start[b * BNOD + t + 256];
  int n = gcur[b] - b * CAP;
  __syncthreads();
  const uint* eb = ebuf + (size_t)b * CAP;
  for (int i = t; i < n; i += 256) {
    uint p = eb[i];
    int r = atomicAdd(&cur[p >> 17], 1);
    esrc[r] = (int)(p & 0x1FFFFu);
  }
}

__global__ void k_ghist(const int* __restrict__ gid, int* __restrict__ gcnt) {
  int i = blockIdx.x * blockDim.x + threadIdx.x;
  if (i < NN) atomicAdd(&gcnt[gid[i]], 1);
}

__global__ void k_ginit(const int* __restrict__ gcnt, float* __restrict__ inv_gcnt,
                        float* __restrict__ out, const float* __restrict__ b_pred) {
  int g = blockIdx.x * blockDim.x + threadIdx.x;
  if (g < NG) {
    inv_gcnt[g] = 1.0f / fmaxf((float)gcnt[g], 1.0f);
    out[g] = b_pred[0];
  }
}

// ---------------- weight prep: Wnt[l][c][k] = bf16(W_node[l][k][c]) ----------------
__global__ void k_wprep(const float* __restrict__ Wn, unsigned short* __restrict__ Wnt) {
  int i = blockIdx.x * 256 + threadIdx.x;   // L*256*128 total
  int l = i >> 15;
  int k = (i >> 7) & 255;
  int c = i & 127;
  float v = Wn[((size_t)l * 256 + k) * HD + c];
  Wnt[((size_t)l * HD + c) * 256 + k] = f2b(v);
}

// ---------------- embedding: Xb = bf16(h @ W_emb)  [N,28]x[28,128] ----------------
__global__ void k_embed(const float* __restrict__ h, const float* __restrict__ W,
                        unsigned short* __restrict__ Xb) {
  __shared__ float w[NA * HD];
  int t = threadIdx.x;
  for (int i = t; i < NA * HD; i += 256) w[i] = W[i];
  __syncthreads();
  int col = t & 127, rh = t >> 7;
  int row0 = blockIdx.x * 16;
  for (int r = rh; r < 16; r += 2) {
    int row = row0 + r;
    const float* hr = h + (size_t)row * NA;
    float acc = 0.f;
#pragma unroll
    for (int k = 0; k < NA; k++) acc += hr[k] * w[k * HD + col];
    Xb[(size_t)row * HD + col] = f2b(acc);
  }
}

// ---------------- aggregation: Cb[v] = bf16(mean_{u->v} Hb[u]) ----------------
// one wave per node; lane holds 2 bf16 columns; 8 edges in flight
__global__ __launch_bounds__(256) void k_agg(const uint* __restrict__ H32,
                      const int* __restrict__ row_start, const int* __restrict__ deg,
                      const int* __restrict__ esrc, const float* __restrict__ inv_deg,
                      uint* __restrict__ C32) {
  int v = blockIdx.x * 4 + (threadIdx.x >> 6);
  int lane = threadIdx.x & 63;
  int rs = __builtin_amdgcn_readfirstlane(row_start[v]);
  int d  = __builtin_amdgcn_readfirstlane(deg[v]);
  float s0 = 0.f, s1 = 0.f, t0 = 0.f, t1 = 0.f;
  float u0 = 0.f, u1 = 0.f, w0 = 0.f, w1 = 0.f;
  int e = 0;
  for (; e + 8 <= d; e += 8) {
    int i0 = esrc[rs + e];
    int i1 = esrc[rs + e + 1];
    int i2 = esrc[rs + e + 2];
    int i3 = esrc[rs + e + 3];
    int i4 = esrc[rs + e + 4];
    int i5 = esrc[rs + e + 5];
    int i6 = esrc[rs + e + 6];
    int i7 = esrc[rs + e + 7];
    uint x0 = H32[(size_t)i0 * 64 + lane];
    uint x1 = H32[(size_t)i1 * 64 + lane];
    uint x2 = H32[(size_t)i2 * 64 + lane];
    uint x3 = H32[(size_t)i3 * 64 + lane];
    uint x4 = H32[(size_t)i4 * 64 + lane];
    uint x5 = H32[(size_t)i5 * 64 + lane];
    uint x6 = H32[(size_t)i6 * 64 + lane];
    uint x7 = H32[(size_t)i7 * 64 + lane];
    s0 += blo(x0); s1 += bhi(x0);
    t0 += blo(x1); t1 += bhi(x1);
    u0 += blo(x2); u1 += bhi(x2);
    w0 += blo(x3); w1 += bhi(x3);
    s0 += blo(x4); s1 += bhi(x4);
    t0 += blo(x5); t1 += bhi(x5);
    u0 += blo(x6); u1 += bhi(x6);
    w0 += blo(x7); w1 += bhi(x7);
  }
  for (; e + 4 <= d; e += 4) {
    int i0 = esrc[rs + e];
    int i1 = esrc[rs + e + 1];
    int i2 = esrc[rs + e + 2];
    int i3 = esrc[rs + e + 3];
    uint x0 = H32[(size_t)i0 * 64 + lane];
    uint x1 = H32[(size_t)i1 * 64 + lane];
    uint x2 = H32[(size_t)i2 * 64 + lane];
    uint x3 = H32[(size_t)i3 * 64 + lane];
    s0 += blo(x0); s1 += bhi(x0);
    t0 += blo(x1); t1 += bhi(x1);
    u0 += blo(x2); u1 += bhi(x2);
    w0 += blo(x3); w1 += bhi(x3);
  }
  for (; e < d; e++) {
    uint x = H32[(size_t)esrc[rs + e] * 64 + lane];
    s0 += blo(x); s1 += bhi(x);
  }
  float id = inv_deg[v];
  float c0 = ((s0 + t0) + (u0 + w0)) * id;
  float c1 = ((s1 + t1) + (u1 + w1)) * id;
  C32[(size_t)v * 64 + lane] = pack2(c0, c1);
}

// ---------------- NodeApply (MFMA): Cio <- bf16(relu([Hb||Cio]@W + b)*snorm + Hb) ----
__global__ __launch_bounds__(256) void k_apply(const unsigned short* __restrict__ Hb,
                                               unsigned short* __restrict__ Cio,
                                               const unsigned short* __restrict__ Wt,
                                               const float* __restrict__ bias,
                                               const float* __restrict__ snorm) {
  int t = threadIdx.x;
  int lane = t & 63, w = t >> 6;
  int wr = w >> 1, wc = w & 1;
  int row0 = blockIdx.x * 64 + wr * 32;
  int col0 = wc * 64;
  int fr = lane & 15;           // A-row / B-col within tile
  int fk = (lane >> 4) * 8;     // k sub-offset

  f32x4 acc[2][4] = {};

#pragma unroll
  for (int ks = 0; ks < 8; ks++) {
    int kb = ks * 32 + fk;      // 0..255 in 8-elem chunks
    bf16x8 a[2];
#pragma unroll
    for (int rt = 0; rt < 2; rt++) {
      int row = row0 + rt * 16 + fr;
      const unsigned short* ap = (kb < HD)
          ? (Hb  + (size_t)row * HD + kb)
          : (Cio + (size_t)row * HD + (kb - HD));
      a[rt] = *(const bf16x8*)ap;
    }
#pragma unroll
    for (int ct = 0; ct < 4; ct++) {
      int col = col0 + ct * 16 + fr;
      bf16x8 b = *(const bf16x8*)(Wt + (size_t)col * 256 + ks * 32 + fk);
#pragma unroll
      for (int rt = 0; rt < 2; rt++)
        acc[rt][ct] = __builtin_amdgcn_mfma_f32_16x16x32_bf16(a[rt], b, acc[rt][ct], 0, 0, 0);
    }
  }

  __syncthreads();   // all reads of Cio in this block done before in-place writes

  int oc = lane & 15;
  int orb = (lane >> 4) * 4;
#pragma unroll
  for (int rt = 0; rt < 2; rt++) {
#pragma unroll
    for (int ct = 0; ct < 4; ct++) {
      int col = col0 + ct * 16 + oc;
      float bv = bias[col];
#pragma unroll
      for (int r = 0; r < 4; r++) {
        int row = row0 + rt * 16 + orb + r;
        float sn = snorm[row];
        float hres = __uint_as_float(((uint)Hb[(size_t)row * HD + col]) << 16);
        float o = fmaxf(acc[rt][ct][r] + bv, 0.f) * sn + hres;
        Cio[(size_t)row * HD + col] = f2b(o);
      }
    }
  }
}

// ---------------- readout ----------------
__global__ void k_wcombo(const float* __restrict__ W_ro, const float* __restrict__ W_pred,
                         float* __restrict__ wcv) {
  int i = threadIdx.x;  // 128
  float a = 0.f;
  for (int j = 0; j < HD; j++) a += W_ro[i * HD + j] * W_pred[j];
  wcv[i] = a;
}

__global__ void k_readout(const uint* __restrict__ H32, const float* __restrict__ wcv,
                          const int* __restrict__ gid, const float* __restrict__ inv_gcnt,
                          float* __restrict__ out) {
  int wave = threadIdx.x >> 6, lane = threadIdx.x & 63;
  int v = blockIdx.x * 4 + wave;
  uint x = H32[(size_t)v * 64 + lane];
  float2 wv = *(const float2*)(wcv + lane * 2);
  float p = blo(x) * wv.x + bhi(x) * wv.y;
#pragma unroll
  for (int o = 32; o > 0; o >>= 1) p += __shfl_down(p, o, 64);
  if (lane == 0) {
    int g = gid[v];
    atomicAdd(&out[g], p * inv_gcnt[g]);
  }
}

// ---------------- launch ----------------
extern "C" void kernel_launch(void* const* d_in, const int* in_sizes, int n_in,
                              void* d_out, int out_size, void* d_ws, size_t ws_size,
                              hipStream_t stream) {
  const float* h      = (const float*)d_in[0];
  const float* snorm  = (const float*)d_in[1];
  const float* W_emb  = (const float*)d_in[2];
  const float* W_node = (const float*)d_in[3];
  const float* b_node = (const float*)d_in[4];
  const float* W_ro   = (const float*)d_in[5];
  const float* W_pred = (const float*)d_in[6];
  const float* b_pred = (const float*)d_in[7];
  const int*   src    = (const int*)d_in[8];
  const int*   dst    = (const int*)d_in[9];
  const int*   gid    = (const int*)d_in[10];
  float* out = (float*)d_out;

  char* ws = (char*)d_ws;
  unsigned short* Xb   = (unsigned short*)(ws + OFF_XB);
  unsigned short* Yb   = (unsigned short*)(ws + OFF_YB);
  int*   esrc     = (int*)(ws + OFF_ESRC);
  int*   deg      = (int*)(ws + OFF_DEG);
  int*   gcnt     = (int*)(ws + OFF_GCNT);
  int*   row_s    = (int*)(ws + OFF_ROW);
  float* inv_deg  = (float*)(ws + OFF_IDEG);
  float* inv_gcnt = (float*)(ws + OFF_IGC);
  int*   bsum     = (int*)(ws + OFF_BSUM);
  int*   coff     = (int*)(ws + OFF_COFF);
  float* wcv      = (float*)(ws + OFF_WC);
  unsigned short* Wnt = (unsigned short*)(ws + OFF_WNT);
  uint*  ebuf     = (uint*)(ws + OFF_EBUF);
  int*   gcur     = (int*)(ws + OFF_GCUR);

  hipMemsetAsync(ws + OFF_GCNT, 0, (size_t)NG * 4, stream);

  k_binit<<<1, NB, 0, stream>>>(gcur);
  k_bin<<<NE / 4096, 256, 0, stream>>>(src, dst, gcur, ebuf);
  k_deg<<<NB, 256, 0, stream>>>(gcur, ebuf, deg);
  k_scan1<<<NN / 1024, 256, 0, stream>>>(deg, bsum);
  k_scan2<<<1, 128, 0, stream>>>(bsum, coff);
  k_scan3<<<NN / 1024, 256, 0, stream>>>(deg, coff, row_s, inv_deg);
  k_place2<<<NB, 256, 0, stream>>>(gcur, ebuf, row_s, esrc);
  k_ghist<<<NN / 256, 256, 0, stream>>>(gid, gcnt);
  k_ginit<<<NG / 256, 256, 0, stream>>>(gcnt, inv_gcnt, out, b_pred);
  k_wprep<<<(NL * 256 * HD) / 256, 256, 0, stream>>>(W_node, Wnt);

  k_embed<<<NN / 16, 256, 0, stream>>>(h, W_emb, Xb);

  for (int l = 0; l < NL; l++) {
    unsigned short* hb = (l & 1) ? Yb : Xb;
    unsigned short* cb = (l & 1) ? Xb : Yb;
    k_agg<<<NN / 4, 256, 0, stream>>>((const uint*)hb, row_s, deg, esrc, inv_deg,
                                      (uint*)cb);
    k_apply<<<NN / 64, 256, 0, stream>>>(hb, cb, Wnt + (size_t)l * HD * 256,
                                         b_node + (size_t)l * HD, snorm);
  }
  // final h is in Xb after 4 layers

  k_wcombo<<<1, 128, 0, stream>>>(W_ro, W_pred, wcv);
  k_readout<<<NN / 4, 256, 0, stream>>>((const uint*)Xb, wcv, gid, inv_gcnt, out);
}

// Round 4
// 714.697 us; speedup vs baseline: 2.6620x; 1.0565x over previous
//
#include <hip/hip_runtime.h>

// Problem constants
constexpr int NN  = 131072;   // nodes
constexpr int NE  = 2097152;  // edges
constexpr int HD  = 128;      // hidden
constexpr int NG  = 8192;     // graphs
constexpr int NA  = 28;       // atom types
constexpr int NL  = 4;        // layers

// CSR bucketing
constexpr int NB   = 256;     // buckets
constexpr int BSH  = 9;       // dst>>9 -> bucket (512 nodes/bucket)
constexpr int BNOD = 512;     // nodes per bucket
constexpr int CAP  = 10240;   // slots per bucket (mean 8192 + 22 sigma)

// ---------------- workspace layout (bytes) ----------------
constexpr size_t SZ_FB   = (size_t)NN * HD * 2;          // 32 MiB bf16 feature buf
constexpr size_t OFF_XB   = 0;
constexpr size_t OFF_YB   = OFF_XB + SZ_FB;
constexpr size_t OFF_ESRC = OFF_YB + SZ_FB;
constexpr size_t OFF_DEG  = OFF_ESRC + (size_t)NE * 4;
constexpr size_t OFF_GCNT = OFF_DEG + (size_t)NN * 4;
constexpr size_t OFF_ROW  = OFF_GCNT + (size_t)NG * 4;
constexpr size_t OFF_IDEG = OFF_ROW + (size_t)NN * 4;
constexpr size_t OFF_IGC  = OFF_IDEG + (size_t)NN * 4;
constexpr size_t OFF_BSUM = OFF_IGC + (size_t)NG * 4;
constexpr size_t OFF_COFF = OFF_BSUM + 512;
constexpr size_t OFF_WC   = OFF_COFF + 512;
constexpr size_t OFF_WNT  = OFF_WC + 512;                // bf16 W transposed [L][128][256]
constexpr size_t OFF_EBUF = OFF_WNT + (size_t)NL * HD * 256 * 2;
constexpr size_t OFF_GCUR = OFF_EBUF + (size_t)NB * CAP * 4;
constexpr size_t OFF_WET  = OFF_GCUR + (size_t)NB * 4;   // bf16 W_emb^T [128][32]

// ---------------- bf16 helpers ----------------
__device__ __forceinline__ float blo(uint x) { return __uint_as_float(x << 16); }
__device__ __forceinline__ float bhi(uint x) { return __uint_as_float(x & 0xFFFF0000u); }
__device__ __forceinline__ unsigned short f2b(float f) {
  uint u = __float_as_uint(f);
  return (unsigned short)((u + 0x7FFFu + ((u >> 16) & 1u)) >> 16);
}
__device__ __forceinline__ uint pack2(float a, float b) {
  uint ua = __float_as_uint(a), ub = __float_as_uint(b);
  uint lo = (ua + 0x7FFFu + ((ua >> 16) & 1u)) >> 16;
  uint hi = (ub + 0x7FFFu + ((ub >> 16) & 1u)) & 0xFFFF0000u;
  return lo | hi;
}

typedef __attribute__((ext_vector_type(8))) short bf16x8;
typedef __attribute__((ext_vector_type(4))) float f32x4;

// ---------------- CSR build: bucketed ----------------
__global__ void k_binit(int* __restrict__ gcur) {
  int b = threadIdx.x;           // 256
  gcur[b] = b * CAP;
}

// partition edges into NB buckets by dst>>BSH; packed = (dst&511)<<17 | src
__global__ __launch_bounds__(256) void k_bin(const int* __restrict__ src,
                                             const int* __restrict__ dst,
                                             int* __restrict__ gcur,
                                             uint* __restrict__ ebuf) {
  __shared__ int cnt[NB];
  __shared__ int gbase[NB];
  int t = threadIdx.x;
  cnt[t] = 0;
  int es[16], ed[16];
  int base = blockIdx.x * 4096 + t;
#pragma unroll
  for (int j = 0; j < 16; j++) {
    es[j] = src[base + j * 256];
    ed[j] = dst[base + j * 256];
  }
  __syncthreads();
#pragma unroll
  for (int j = 0; j < 16; j++) atomicAdd(&cnt[ed[j] >> BSH], 1);
  __syncthreads();
  int c = cnt[t];
  if (c > 0) gbase[t] = atomicAdd(&gcur[t], c);
  cnt[t] = 0;
  __syncthreads();
#pragma unroll
  for (int j = 0; j < 16; j++) {
    int b = ed[j] >> BSH;
    int r = atomicAdd(&cnt[b], 1);
    ebuf[(size_t)gbase[b] + r] = ((uint)(ed[j] & (BNOD - 1)) << 17) | (uint)es[j];
  }
}

// per-bucket degree histogram (LDS), coalesced deg writes, no global atomics
__global__ __launch_bounds__(256) void k_deg(const int* __restrict__ gcur,
                                             const uint* __restrict__ ebuf,
                                             int* __restrict__ deg) {
  __shared__ int h[BNOD];
  int b = blockIdx.x, t = threadIdx.x;
  h[t] = 0; h[t + 256] = 0;
  int n = gcur[b] - b * CAP;
  __syncthreads();
  const uint* eb = ebuf + (size_t)b * CAP;
  for (int i = t; i < n; i += 256) atomicAdd(&h[eb[i] >> 17], 1);
  __syncthreads();
  deg[b * BNOD + t] = h[t];
  deg[b * BNOD + t + 256] = h[t + 256];
}

__global__ void k_scan1(const int* __restrict__ deg, int* __restrict__ bsum) {
  __shared__ int s[256];
  int b = blockIdx.x, t = threadIdx.x;
  const int4* p = (const int4*)(deg + (size_t)b * 1024);
  int4 v = p[t];
  s[t] = v.x + v.y + v.z + v.w;
  __syncthreads();
  for (int o = 128; o > 0; o >>= 1) {
    if (t < o) s[t] += s[t + o];
    __syncthreads();
  }
  if (t == 0) bsum[b] = s[0];
}

__global__ void k_scan2(const int* __restrict__ bsum, int* __restrict__ coff) {
  __shared__ int s[128];
  int t = threadIdx.x;
  int mine = bsum[t];
  s[t] = mine;
  __syncthreads();
  for (int o = 1; o < 128; o <<= 1) {
    int v = (t >= o) ? s[t - o] : 0;
    __syncthreads();
    s[t] += v;
    __syncthreads();
  }
  coff[t] = s[t] - mine;  // exclusive
}

__global__ void k_scan3(const int* __restrict__ deg, const int* __restrict__ coff,
                        int* __restrict__ row_start, float* __restrict__ inv_deg) {
  __shared__ int s[256];
  int b = blockIdx.x, t = threadIdx.x;
  int base = b * 1024 + t * 4;
  const int4* p = (const int4*)(deg + base);
  int4 d = *p;
  int lsum = d.x + d.y + d.z + d.w;
  s[t] = lsum;
  __syncthreads();
  for (int o = 1; o < 256; o <<= 1) {
    int v = (t >= o) ? s[t - o] : 0;
    __syncthreads();
    s[t] += v;
    __syncthreads();
  }
  int pre = coff[b] + s[t] - lsum;
  int r0 = pre, r1 = r0 + d.x, r2 = r1 + d.y, r3 = r2 + d.z;
  row_start[base] = r0;  row_start[base + 1] = r1;
  row_start[base + 2] = r2;  row_start[base + 3] = r3;
  inv_deg[base]     = 1.0f / fmaxf((float)d.x, 1.0f);
  inv_deg[base + 1] = 1.0f / fmaxf((float)d.y, 1.0f);
  inv_deg[base + 2] = 1.0f / fmaxf((float)d.z, 1.0f);
  inv_deg[base + 3] = 1.0f / fmaxf((float)d.w, 1.0f);
}

// per-bucket placement: LDS cursors, esrc writes land in a 32KB window
__global__ __launch_bounds__(256) void k_place2(const int* __restrict__ gcur,
                                                const uint* __restrict__ ebuf,
                                                const int* __restrict__ row_start,
                                                int* __restrict__ esrc) {
  __shared__ int cur[BNOD];
  int b = blockIdx.x, t = threadIdx.x;
  cur[t] = row_start[b * BNOD + t];
  cur[t + 256] = row_start[b * BNOD + t + 256];
  int n = gcur[b] - b * CAP;
  __syncthreads();
  const uint* eb = ebuf + (size_t)b * CAP;
  for (int i = t; i < n; i += 256) {
    uint p = eb[i];
    int r = atomicAdd(&cur[p >> 17], 1);
    esrc[r] = (int)(p & 0x1FFFFu);
  }
}

__global__ void k_ghist(const int* __restrict__ gid, int* __restrict__ gcnt) {
  int i = blockIdx.x * blockDim.x + threadIdx.x;
  if (i < NN) atomicAdd(&gcnt[gid[i]], 1);
}

__global__ void k_ginit(const int* __restrict__ gcnt, float* __restrict__ inv_gcnt,
                        float* __restrict__ out, const float* __restrict__ b_pred) {
  int g = blockIdx.x * blockDim.x + threadIdx.x;
  if (g < NG) {
    inv_gcnt[g] = 1.0f / fmaxf((float)gcnt[g], 1.0f);
    out[g] = b_pred[0];
  }
}

// ---------------- weight prep ----------------
// Wnt[l][c][k] = bf16(W_node[l][k][c])
__global__ void k_wprep(const float* __restrict__ Wn, unsigned short* __restrict__ Wnt) {
  int i = blockIdx.x * 256 + threadIdx.x;   // L*256*128 total
  int l = i >> 15;
  int k = (i >> 7) & 255;
  int c = i & 127;
  float v = Wn[((size_t)l * 256 + k) * HD + c];
  Wnt[((size_t)l * HD + c) * 256 + k] = f2b(v);
}

// Wet[c][k] = bf16(W_emb[k][c]), k padded 28->32 with zeros
__global__ void k_weprep(const float* __restrict__ We, unsigned short* __restrict__ Wet) {
  int i = blockIdx.x * 256 + threadIdx.x;   // 128*32 = 4096 total
  int col = i >> 5, k = i & 31;
  Wet[i] = (k < NA) ? f2b(We[(size_t)k * HD + col]) : (unsigned short)0;
}

// ---------------- embedding (MFMA): Xb = bf16(h @ W_emb) ----------------
// block: 64 rows x 128 cols, 4 waves 2x2; K=32 (padded from 28)
__global__ __launch_bounds__(256) void k_embed(const float* __restrict__ h,
                                               const unsigned short* __restrict__ Wet,
                                               unsigned short* __restrict__ Xb) {
  int t = threadIdx.x;
  int lane = t & 63, w = t >> 6;
  int wr = w >> 1, wc = w & 1;
  int row0 = blockIdx.x * 64 + wr * 32;
  int col0 = wc * 64;
  int fr = lane & 15;
  int fk = (lane >> 4) * 8;

  f32x4 acc[2][4] = {};
  bf16x8 a[2];
#pragma unroll
  for (int rt = 0; rt < 2; rt++) {
    int row = row0 + rt * 16 + fr;
    const float* hp = h + (size_t)row * NA + fk;
    float4 p = *(const float4*)hp;                    // k = fk..fk+3 (always < 28)
    float4 q = make_float4(0.f, 0.f, 0.f, 0.f);
    if (fk < 24) q = *(const float4*)(hp + 4);        // k = fk+4..fk+7; fk==24 -> pad 0
    a[rt][0] = (short)f2b(p.x); a[rt][1] = (short)f2b(p.y);
    a[rt][2] = (short)f2b(p.z); a[rt][3] = (short)f2b(p.w);
    a[rt][4] = (short)f2b(q.x); a[rt][5] = (short)f2b(q.y);
    a[rt][6] = (short)f2b(q.z); a[rt][7] = (short)f2b(q.w);
  }
#pragma unroll
  for (int ct = 0; ct < 4; ct++) {
    int col = col0 + ct * 16 + fr;
    bf16x8 b = *(const bf16x8*)(Wet + (size_t)col * 32 + fk);
#pragma unroll
    for (int rt = 0; rt < 2; rt++)
      acc[rt][ct] = __builtin_amdgcn_mfma_f32_16x16x32_bf16(a[rt], b, acc[rt][ct], 0, 0, 0);
  }
  int oc = lane & 15, orb = (lane >> 4) * 4;
#pragma unroll
  for (int rt = 0; rt < 2; rt++) {
#pragma unroll
    for (int ct = 0; ct < 4; ct++) {
      int col = col0 + ct * 16 + oc;
#pragma unroll
      for (int r = 0; r < 4; r++) {
        int row = row0 + rt * 16 + orb + r;
        Xb[(size_t)row * HD + col] = f2b(acc[rt][ct][r]);
      }
    }
  }
}

// ---------------- aggregation: Cb[v] = bf16(mean_{u->v} Hb[u]) ----------------
// one wave per node; 32 lanes cover a 256B row (uint2/lane); 2 edges per load
// instruction via lane-half select; 8 loads (16 edges) in flight
__global__ __launch_bounds__(256) void k_agg(const uint2* __restrict__ H64,
                      const int* __restrict__ row_start, const int* __restrict__ deg,
                      const int* __restrict__ esrc, const float* __restrict__ inv_deg,
                      uint2* __restrict__ C64) {
  int v = blockIdx.x * 4 + (threadIdx.x >> 6);
  int lane = threadIdx.x & 63;
  int half = lane >> 5;
  int cl = lane & 31;                       // cols cl*4 .. cl*4+3
  int rs = __builtin_amdgcn_readfirstlane(row_start[v]);
  int d  = __builtin_amdgcn_readfirstlane(deg[v]);
  float a0 = 0.f, a1 = 0.f, a2 = 0.f, a3 = 0.f;
  float b0 = 0.f, b1 = 0.f, b2 = 0.f, b3 = 0.f;
  int e = 0;
  for (; e + 16 <= d; e += 16) {
    uint2 x[8];
#pragma unroll
    for (int j = 0; j < 8; j++) {
      int ea = esrc[rs + e + 2 * j];        // scalar loads (uniform addr)
      int eb = esrc[rs + e + 2 * j + 1];
      int idx = half ? eb : ea;
      x[j] = H64[(size_t)idx * 32 + cl];
    }
#pragma unroll
    for (int j = 0; j < 8; j++) {
      if (j & 1) { b0 += blo(x[j].x); b1 += bhi(x[j].x); b2 += blo(x[j].y); b3 += bhi(x[j].y); }
      else       { a0 += blo(x[j].x); a1 += bhi(x[j].x); a2 += blo(x[j].y); a3 += bhi(x[j].y); }
    }
  }
  for (; e + 2 <= d; e += 2) {
    int ea = esrc[rs + e], eb = esrc[rs + e + 1];
    int idx = half ? eb : ea;
    uint2 x = H64[(size_t)idx * 32 + cl];
    b0 += blo(x.x); b1 += bhi(x.x); b2 += blo(x.y); b3 += bhi(x.y);
  }
  if (e < d) {
    int idx = esrc[rs + e];
    uint2 x = H64[(size_t)idx * 32 + cl];
    if (half == 0) { a0 += blo(x.x); a1 += bhi(x.x); a2 += blo(x.y); a3 += bhi(x.y); }
  }
  a0 += b0; a1 += b1; a2 += b2; a3 += b3;
  a0 += __shfl_xor(a0, 32, 64);
  a1 += __shfl_xor(a1, 32, 64);
  a2 += __shfl_xor(a2, 32, 64);
  a3 += __shfl_xor(a3, 32, 64);
  float id = inv_deg[v];
  if (half == 0) {
    uint2 o;
    o.x = pack2(a0 * id, a1 * id);
    o.y = pack2(a2 * id, a3 * id);
    C64[(size_t)v * 32 + cl] = o;
  }
}

// ---------------- NodeApply (MFMA): Cio <- bf16(relu([Hb||Cio]@W + b)*snorm + Hb) ----
// block: 128 rows x 128 cols, 4 waves 2x2 (wave tile 64x64, acc[4][4])
__global__ __launch_bounds__(256) void k_apply(const unsigned short* __restrict__ Hb,
                                               unsigned short* __restrict__ Cio,
                                               const unsigned short* __restrict__ Wt,
                                               const float* __restrict__ bias,
                                               const float* __restrict__ snorm) {
  int t = threadIdx.x;
  int lane = t & 63, w = t >> 6;
  int wr = w >> 1, wc = w & 1;
  int row0 = blockIdx.x * 128 + wr * 64;
  int col0 = wc * 64;
  int fr = lane & 15;           // A-row / B-col within tile
  int fk = (lane >> 4) * 8;     // k sub-offset

  f32x4 acc[4][4] = {};

#pragma unroll
  for (int ks = 0; ks < 8; ks++) {
    int kb = ks * 32 + fk;      // 0..255 in 8-elem chunks
    bf16x8 a[4];
#pragma unroll
    for (int rt = 0; rt < 4; rt++) {
      int row = row0 + rt * 16 + fr;
      const unsigned short* ap = (kb < HD)
          ? (Hb  + (size_t)row * HD + kb)
          : (Cio + (size_t)row * HD + (kb - HD));
      a[rt] = *(const bf16x8*)ap;
    }
#pragma unroll
    for (int ct = 0; ct < 4; ct++) {
      int col = col0 + ct * 16 + fr;
      bf16x8 b = *(const bf16x8*)(Wt + (size_t)col * 256 + ks * 32 + fk);
#pragma unroll
      for (int rt = 0; rt < 4; rt++)
        acc[rt][ct] = __builtin_amdgcn_mfma_f32_16x16x32_bf16(a[rt], b, acc[rt][ct], 0, 0, 0);
    }
  }

  __syncthreads();   // all reads of Cio in this block done before in-place writes

  int oc = lane & 15;
  int orb = (lane >> 4) * 4;
#pragma unroll
  for (int rt = 0; rt < 4; rt++) {
#pragma unroll
    for (int ct = 0; ct < 4; ct++) {
      int col = col0 + ct * 16 + oc;
      float bv = bias[col];
#pragma unroll
      for (int r = 0; r < 4; r++) {
        int row = row0 + rt * 16 + orb + r;
        float sn = snorm[row];
        float hres = __uint_as_float(((uint)Hb[(size_t)row * HD + col]) << 16);
        float o = fmaxf(acc[rt][ct][r] + bv, 0.f) * sn + hres;
        Cio[(size_t)row * HD + col] = f2b(o);
      }
    }
  }
}

// ---------------- readout ----------------
__global__ void k_wcombo(const float* __restrict__ W_ro, const float* __restrict__ W_pred,
                         float* __restrict__ wcv) {
  int i = threadIdx.x;  // 128
  float a = 0.f;
  for (int j = 0; j < HD; j++) a += W_ro[i * HD + j] * W_pred[j];
  wcv[i] = a;
}

__global__ void k_readout(const uint* __restrict__ H32, const float* __restrict__ wcv,
                          const int* __restrict__ gid, const float* __restrict__ inv_gcnt,
                          float* __restrict__ out) {
  int wave = threadIdx.x >> 6, lane = threadIdx.x & 63;
  int v = blockIdx.x * 4 + wave;
  uint x = H32[(size_t)v * 64 + lane];
  float2 wv = *(const float2*)(wcv + lane * 2);
  float p = blo(x) * wv.x + bhi(x) * wv.y;
#pragma unroll
  for (int o = 32; o > 0; o >>= 1) p += __shfl_down(p, o, 64);
  if (lane == 0) {
    int g = gid[v];
    atomicAdd(&out[g], p * inv_gcnt[g]);
  }
}

// ---------------- launch ----------------
extern "C" void kernel_launch(void* const* d_in, const int* in_sizes, int n_in,
                              void* d_out, int out_size, void* d_ws, size_t ws_size,
                              hipStream_t stream) {
  const float* h      = (const float*)d_in[0];
  const float* snorm  = (const float*)d_in[1];
  const float* W_emb  = (const float*)d_in[2];
  const float* W_node = (const float*)d_in[3];
  const float* b_node = (const float*)d_in[4];
  const float* W_ro   = (const float*)d_in[5];
  const float* W_pred = (const float*)d_in[6];
  const float* b_pred = (const float*)d_in[7];
  const int*   src    = (const int*)d_in[8];
  const int*   dst    = (const int*)d_in[9];
  const int*   gid    = (const int*)d_in[10];
  float* out = (float*)d_out;

  char* ws = (char*)d_ws;
  unsigned short* Xb   = (unsigned short*)(ws + OFF_XB);
  unsigned short* Yb   = (unsigned short*)(ws + OFF_YB);
  int*   esrc     = (int*)(ws + OFF_ESRC);
  int*   deg      = (int*)(ws + OFF_DEG);
  int*   gcnt     = (int*)(ws + OFF_GCNT);
  int*   row_s    = (int*)(ws + OFF_ROW);
  float* inv_deg  = (float*)(ws + OFF_IDEG);
  float* inv_gcnt = (float*)(ws + OFF_IGC);
  int*   bsum     = (int*)(ws + OFF_BSUM);
  int*   coff     = (int*)(ws + OFF_COFF);
  float* wcv      = (float*)(ws + OFF_WC);
  unsigned short* Wnt = (unsigned short*)(ws + OFF_WNT);
  uint*  ebuf     = (uint*)(ws + OFF_EBUF);
  int*   gcur     = (int*)(ws + OFF_GCUR);
  unsigned short* Wet = (unsigned short*)(ws + OFF_WET);

  hipMemsetAsync(ws + OFF_GCNT, 0, (size_t)NG * 4, stream);

  k_binit<<<1, NB, 0, stream>>>(gcur);
  k_bin<<<NE / 4096, 256, 0, stream>>>(src, dst, gcur, ebuf);
  k_deg<<<NB, 256, 0, stream>>>(gcur, ebuf, deg);
  k_scan1<<<NN / 1024, 256, 0, stream>>>(deg, bsum);
  k_scan2<<<1, 128, 0, stream>>>(bsum, coff);
  k_scan3<<<NN / 1024, 256, 0, stream>>>(deg, coff, row_s, inv_deg);
  k_place2<<<NB, 256, 0, stream>>>(gcur, ebuf, row_s, esrc);
  k_ghist<<<NN / 256, 256, 0, stream>>>(gid, gcnt);
  k_ginit<<<NG / 256, 256, 0, stream>>>(gcnt, inv_gcnt, out, b_pred);
  k_wprep<<<(NL * 256 * HD) / 256, 256, 0, stream>>>(W_node, Wnt);
  k_weprep<<<(HD * 32) / 256, 256, 0, stream>>>(W_emb, Wet);

  k_embed<<<NN / 64, 256, 0, stream>>>(h, Wet, Xb);

  for (int l = 0; l < NL; l++) {
    unsigned short* hb = (l & 1) ? Yb : Xb;
    unsigned short* cb = (l & 1) ? Xb : Yb;
    k_agg<<<NN / 4, 256, 0, stream>>>((const uint2*)hb, row_s, deg, esrc, inv_deg,
                                      (uint2*)cb);
    k_apply<<<NN / 128, 256, 0, stream>>>(hb, cb, Wnt + (size_t)l * HD * 256,
                                          b_node + (size_t)l * HD, snorm);
  }
  // final h is in Xb after 4 layers

  k_wcombo<<<1, 128, 0, stream>>>(W_ro, W_pred, wcv);
  k_readout<<<NN / 4, 256, 0, stream>>>((const uint*)Xb, wcv, gid, inv_gcnt, out);
}

// Round 5
// 711.309 us; speedup vs baseline: 2.6746x; 1.0048x over previous
//
#include <hip/hip_runtime.h>

// Problem constants
constexpr int NN  = 131072;   // nodes
constexpr int NE  = 2097152;  // edges
constexpr int HD  = 128;      // hidden
constexpr int NG  = 8192;     // graphs
constexpr int NA  = 28;       // atom types
constexpr int NL  = 4;        // layers

// CSR bucketing
constexpr int NB   = 256;     // buckets
constexpr int BSH  = 9;       // dst>>9 -> bucket (512 nodes/bucket)
constexpr int BNOD = 512;     // nodes per bucket
constexpr int CAP  = 10240;   // slots per bucket (mean 8192 + 22 sigma)

// ---------------- workspace layout (bytes) ----------------
constexpr size_t SZ_FB   = (size_t)NN * HD * 2;          // 32 MiB bf16 feature buf
constexpr size_t OFF_XB   = 0;
constexpr size_t OFF_YB   = OFF_XB + SZ_FB;
constexpr size_t OFF_ESRC = OFF_YB + SZ_FB;
constexpr size_t OFF_DEG  = OFF_ESRC + (size_t)NE * 4;
constexpr size_t OFF_GCNT = OFF_DEG + (size_t)NN * 4;
constexpr size_t OFF_ROW  = OFF_GCNT + (size_t)NG * 4;
constexpr size_t OFF_IDEG = OFF_ROW + (size_t)NN * 4;
constexpr size_t OFF_IGC  = OFF_IDEG + (size_t)NN * 4;
constexpr size_t OFF_BSUM = OFF_IGC + (size_t)NG * 4;
constexpr size_t OFF_COFF = OFF_BSUM + 512;
constexpr size_t OFF_WC   = OFF_COFF + 512;
constexpr size_t OFF_WNT  = OFF_WC + 512;                // bf16 W transposed [L][128][256]
constexpr size_t OFF_EBUF = OFF_WNT + (size_t)NL * HD * 256 * 2;
constexpr size_t OFF_GCUR = OFF_EBUF + (size_t)NB * CAP * 4;
constexpr size_t OFF_WET  = OFF_GCUR + (size_t)NB * 4;   // bf16 W_emb^T [128][32]

// ---------------- bf16 helpers ----------------
__device__ __forceinline__ float blo(uint x) { return __uint_as_float(x << 16); }
__device__ __forceinline__ float bhi(uint x) { return __uint_as_float(x & 0xFFFF0000u); }
__device__ __forceinline__ unsigned short f2b(float f) {
  uint u = __float_as_uint(f);
  return (unsigned short)((u + 0x7FFFu + ((u >> 16) & 1u)) >> 16);
}
__device__ __forceinline__ uint pack2(float a, float b) {
  uint ua = __float_as_uint(a), ub = __float_as_uint(b);
  uint lo = (ua + 0x7FFFu + ((ua >> 16) & 1u)) >> 16;
  uint hi = (ub + 0x7FFFu + ((ub >> 16) & 1u)) & 0xFFFF0000u;
  return lo | hi;
}

typedef __attribute__((ext_vector_type(8))) short bf16x8;
typedef __attribute__((ext_vector_type(4))) float f32x4;

// ---------------- CSR build: bucketed ----------------
__global__ void k_binit(int* __restrict__ gcur) {
  int b = threadIdx.x;           // 256
  gcur[b] = b * CAP;
}

// partition edges into NB buckets by dst>>BSH; packed = (dst&511)<<17 | src
__global__ __launch_bounds__(256) void k_bin(const int* __restrict__ src,
                                             const int* __restrict__ dst,
                                             int* __restrict__ gcur,
                                             uint* __restrict__ ebuf) {
  __shared__ int cnt[NB];
  __shared__ int gbase[NB];
  int t = threadIdx.x;
  cnt[t] = 0;
  int es[16], ed[16];
  int base = blockIdx.x * 4096 + t;
#pragma unroll
  for (int j = 0; j < 16; j++) {
    es[j] = src[base + j * 256];
    ed[j] = dst[base + j * 256];
  }
  __syncthreads();
#pragma unroll
  for (int j = 0; j < 16; j++) atomicAdd(&cnt[ed[j] >> BSH], 1);
  __syncthreads();
  int c = cnt[t];
  if (c > 0) gbase[t] = atomicAdd(&gcur[t], c);
  cnt[t] = 0;
  __syncthreads();
#pragma unroll
  for (int j = 0; j < 16; j++) {
    int b = ed[j] >> BSH;
    int r = atomicAdd(&cnt[b], 1);
    ebuf[(size_t)gbase[b] + r] = ((uint)(ed[j] & (BNOD - 1)) << 17) | (uint)es[j];
  }
}

// per-bucket degree histogram (LDS), coalesced deg writes, no global atomics
__global__ __launch_bounds__(256) void k_deg(const int* __restrict__ gcur,
                                             const uint* __restrict__ ebuf,
                                             int* __restrict__ deg) {
  __shared__ int h[BNOD];
  int b = blockIdx.x, t = threadIdx.x;
  h[t] = 0; h[t + 256] = 0;
  int n = gcur[b] - b * CAP;
  __syncthreads();
  const uint* eb = ebuf + (size_t)b * CAP;
  for (int i = t; i < n; i += 256) atomicAdd(&h[eb[i] >> 17], 1);
  __syncthreads();
  deg[b * BNOD + t] = h[t];
  deg[b * BNOD + t + 256] = h[t + 256];
}

__global__ void k_scan1(const int* __restrict__ deg, int* __restrict__ bsum) {
  __shared__ int s[256];
  int b = blockIdx.x, t = threadIdx.x;
  const int4* p = (const int4*)(deg + (size_t)b * 1024);
  int4 v = p[t];
  s[t] = v.x + v.y + v.z + v.w;
  __syncthreads();
  for (int o = 128; o > 0; o >>= 1) {
    if (t < o) s[t] += s[t + o];
    __syncthreads();
  }
  if (t == 0) bsum[b] = s[0];
}

__global__ void k_scan2(const int* __restrict__ bsum, int* __restrict__ coff) {
  __shared__ int s[128];
  int t = threadIdx.x;
  int mine = bsum[t];
  s[t] = mine;
  __syncthreads();
  for (int o = 1; o < 128; o <<= 1) {
    int v = (t >= o) ? s[t - o] : 0;
    __syncthreads();
    s[t] += v;
    __syncthreads();
  }
  coff[t] = s[t] - mine;  // exclusive
}

__global__ void k_scan3(const int* __restrict__ deg, const int* __restrict__ coff,
                        int* __restrict__ row_start, float* __restrict__ inv_deg) {
  __shared__ int s[256];
  int b = blockIdx.x, t = threadIdx.x;
  int base = b * 1024 + t * 4;
  const int4* p = (const int4*)(deg + base);
  int4 d = *p;
  int lsum = d.x + d.y + d.z + d.w;
  s[t] = lsum;
  __syncthreads();
  for (int o = 1; o < 256; o <<= 1) {
    int v = (t >= o) ? s[t - o] : 0;
    __syncthreads();
    s[t] += v;
    __syncthreads();
  }
  int pre = coff[b] + s[t] - lsum;
  int r0 = pre, r1 = r0 + d.x, r2 = r1 + d.y, r3 = r2 + d.z;
  row_start[base] = r0;  row_start[base + 1] = r1;
  row_start[base + 2] = r2;  row_start[base + 3] = r3;
  inv_deg[base]     = 1.0f / fmaxf((float)d.x, 1.0f);
  inv_deg[base + 1] = 1.0f / fmaxf((float)d.y, 1.0f);
  inv_deg[base + 2] = 1.0f / fmaxf((float)d.z, 1.0f);
  inv_deg[base + 3] = 1.0f / fmaxf((float)d.w, 1.0f);
}

// per-bucket placement: LDS cursors, esrc writes land in a 32KB window
__global__ __launch_bounds__(256) void k_place2(const int* __restrict__ gcur,
                                                const uint* __restrict__ ebuf,
                                                const int* __restrict__ row_start,
                                                int* __restrict__ esrc) {
  __shared__ int cur[BNOD];
  int b = blockIdx.x, t = threadIdx.x;
  cur[t] = row_start[b * BNOD + t];
  cur[t + 256] = row_start[b * BNOD + t + 256];
  int n = gcur[b] - b * CAP;
  __syncthreads();
  const uint* eb = ebuf + (size_t)b * CAP;
  for (int i = t; i < n; i += 256) {
    uint p = eb[i];
    int r = atomicAdd(&cur[p >> 17], 1);
    esrc[r] = (int)(p & 0x1FFFFu);
  }
}

__global__ void k_ghist(const int* __restrict__ gid, int* __restrict__ gcnt) {
  int i = blockIdx.x * blockDim.x + threadIdx.x;
  if (i < NN) atomicAdd(&gcnt[gid[i]], 1);
}

__global__ void k_ginit(const int* __restrict__ gcnt, float* __restrict__ inv_gcnt,
                        float* __restrict__ out, const float* __restrict__ b_pred) {
  int g = blockIdx.x * blockDim.x + threadIdx.x;
  if (g < NG) {
    inv_gcnt[g] = 1.0f / fmaxf((float)gcnt[g], 1.0f);
    out[g] = b_pred[0];
  }
}

// ---------------- weight prep ----------------
// Wnt[l][c][k] = bf16(W_node[l][k][c])
__global__ void k_wprep(const float* __restrict__ Wn, unsigned short* __restrict__ Wnt) {
  int i = blockIdx.x * 256 + threadIdx.x;   // L*256*128 total
  int l = i >> 15;
  int k = (i >> 7) & 255;
  int c = i & 127;
  float v = Wn[((size_t)l * 256 + k) * HD + c];
  Wnt[((size_t)l * HD + c) * 256 + k] = f2b(v);
}

// Wet[c][k] = bf16(W_emb[k][c]), k padded 28->32 with zeros
__global__ void k_weprep(const float* __restrict__ We, unsigned short* __restrict__ Wet) {
  int i = blockIdx.x * 256 + threadIdx.x;   // 128*32 = 4096 total
  int col = i >> 5, k = i & 31;
  Wet[i] = (k < NA) ? f2b(We[(size_t)k * HD + col]) : (unsigned short)0;
}

// ---------------- embedding (MFMA): Xb = bf16(h @ W_emb) ----------------
// block: 64 rows x 128 cols, 4 waves 2x2; K=32 (padded from 28)
__global__ __launch_bounds__(256) void k_embed(const float* __restrict__ h,
                                               const unsigned short* __restrict__ Wet,
                                               unsigned short* __restrict__ Xb) {
  int t = threadIdx.x;
  int lane = t & 63, w = t >> 6;
  int wr = w >> 1, wc = w & 1;
  int row0 = blockIdx.x * 64 + wr * 32;
  int col0 = wc * 64;
  int fr = lane & 15;
  int fk = (lane >> 4) * 8;

  f32x4 acc[2][4] = {};
  bf16x8 a[2];
#pragma unroll
  for (int rt = 0; rt < 2; rt++) {
    int row = row0 + rt * 16 + fr;
    const float* hp = h + (size_t)row * NA + fk;
    float4 p = *(const float4*)hp;                    // k = fk..fk+3 (always < 28)
    float4 q = make_float4(0.f, 0.f, 0.f, 0.f);
    if (fk < 24) q = *(const float4*)(hp + 4);        // k = fk+4..fk+7; fk==24 -> pad 0
    a[rt][0] = (short)f2b(p.x); a[rt][1] = (short)f2b(p.y);
    a[rt][2] = (short)f2b(p.z); a[rt][3] = (short)f2b(p.w);
    a[rt][4] = (short)f2b(q.x); a[rt][5] = (short)f2b(q.y);
    a[rt][6] = (short)f2b(q.z); a[rt][7] = (short)f2b(q.w);
  }
#pragma unroll
  for (int ct = 0; ct < 4; ct++) {
    int col = col0 + ct * 16 + fr;
    bf16x8 b = *(const bf16x8*)(Wet + (size_t)col * 32 + fk);
#pragma unroll
    for (int rt = 0; rt < 2; rt++)
      acc[rt][ct] = __builtin_amdgcn_mfma_f32_16x16x32_bf16(a[rt], b, acc[rt][ct], 0, 0, 0);
  }
  int oc = lane & 15, orb = (lane >> 4) * 4;
#pragma unroll
  for (int rt = 0; rt < 2; rt++) {
#pragma unroll
    for (int ct = 0; ct < 4; ct++) {
      int col = col0 + ct * 16 + oc;
#pragma unroll
      for (int r = 0; r < 4; r++) {
        int row = row0 + rt * 16 + orb + r;
        Xb[(size_t)row * HD + col] = f2b(acc[rt][ct][r]);
      }
    }
  }
}

// ---------------- fused layer: gather->LDS, MFMA apply, write Ho ----------------
// block: 64 rows; phase 1: 4 waves x 16 nodes gather (uint2 half-select, 8 loads
// in flight); phase 2: 64x128 MFMA tile, A-low from global Hb, A-high from LDS.
__global__ __launch_bounds__(256) void k_layer(const unsigned short* __restrict__ Hb,
                                               unsigned short* __restrict__ Ho,
                                               const int* __restrict__ row_start,
                                               const int* __restrict__ deg,
                                               const int* __restrict__ esrc,
                                               const float* __restrict__ inv_deg,
                                               const unsigned short* __restrict__ Wt,
                                               const float* __restrict__ bias,
                                               const float* __restrict__ snorm) {
  __shared__ unsigned short Cs[64 * HD];    // 16 KB, XOR-swizzled 16B slots
  int t = threadIdx.x;
  int lane = t & 63, w = t >> 6;
  int row0 = blockIdx.x * 64;
  const uint2* H64 = (const uint2*)Hb;
  int half = lane >> 5, cl = lane & 31;

  // ---- phase 1: gather c rows into LDS ----
  for (int i = 0; i < 16; i++) {
    int r = w * 16 + i;                     // local row
    int v = row0 + r;
    int rs = __builtin_amdgcn_readfirstlane(row_start[v]);
    int d  = __builtin_amdgcn_readfirstlane(deg[v]);
    float a0 = 0.f, a1 = 0.f, a2 = 0.f, a3 = 0.f;
    float b0 = 0.f, b1 = 0.f, b2 = 0.f, b3 = 0.f;
    int e = 0;
    for (; e + 16 <= d; e += 16) {
      uint2 x[8];
#pragma unroll
      for (int j = 0; j < 8; j++) {
        int ea = esrc[rs + e + 2 * j];
        int eb = esrc[rs + e + 2 * j + 1];
        int idx = half ? eb : ea;
        x[j] = H64[(size_t)idx * 32 + cl];
      }
#pragma unroll
      for (int j = 0; j < 8; j++) {
        if (j & 1) { b0 += blo(x[j].x); b1 += bhi(x[j].x); b2 += blo(x[j].y); b3 += bhi(x[j].y); }
        else       { a0 += blo(x[j].x); a1 += bhi(x[j].x); a2 += blo(x[j].y); a3 += bhi(x[j].y); }
      }
    }
    for (; e + 2 <= d; e += 2) {
      int ea = esrc[rs + e], eb = esrc[rs + e + 1];
      int idx = half ? eb : ea;
      uint2 x = H64[(size_t)idx * 32 + cl];
      b0 += blo(x.x); b1 += bhi(x.x); b2 += blo(x.y); b3 += bhi(x.y);
    }
    if (e < d) {
      int idx = esrc[rs + e];
      uint2 x = H64[(size_t)idx * 32 + cl];
      if (half == 0) { a0 += blo(x.x); a1 += bhi(x.x); a2 += blo(x.y); a3 += bhi(x.y); }
    }
    a0 += b0; a1 += b1; a2 += b2; a3 += b3;
    a0 += __shfl_xor(a0, 32, 64);
    a1 += __shfl_xor(a1, 32, 64);
    a2 += __shfl_xor(a2, 32, 64);
    a3 += __shfl_xor(a3, 32, 64);
    if (half == 0) {
      float id = inv_deg[v];
      uint2 o;
      o.x = pack2(a0 * id, a1 * id);
      o.y = pack2(a2 * id, a3 * id);
      uint boff = ((uint)r * 256 + (uint)cl * 8) ^ (uint)((r & 7) << 4);
      *(uint2*)((char*)Cs + boff) = o;
    }
  }
  __syncthreads();

  // ---- phase 2: MFMA 64x128 tile; 4 waves 2x2 (wave tile 32x64) ----
  int wr = w >> 1, wc = w & 1;
  int trow0 = wr * 32;
  int col0 = wc * 64;
  int fr = lane & 15;
  int fk = (lane >> 4) * 8;

  f32x4 acc[2][4] = {};
#pragma unroll
  for (int ks = 0; ks < 8; ks++) {
    int kb = ks * 32 + fk;
    bf16x8 a[2];
#pragma unroll
    for (int rt = 0; rt < 2; rt++) {
      int r = trow0 + rt * 16 + fr;
      if (kb < HD) {
        a[rt] = *(const bf16x8*)(Hb + (size_t)(row0 + r) * HD + kb);
      } else {
        uint boff = ((uint)r * 256 + (uint)(kb - HD) * 2) ^ (uint)((r & 7) << 4);
        a[rt] = *(const bf16x8*)((const char*)Cs + boff);
      }
    }
#pragma unroll
    for (int ct = 0; ct < 4; ct++) {
      int col = col0 + ct * 16 + fr;
      bf16x8 b = *(const bf16x8*)(Wt + (size_t)col * 256 + ks * 32 + fk);
#pragma unroll
      for (int rt = 0; rt < 2; rt++)
        acc[rt][ct] = __builtin_amdgcn_mfma_f32_16x16x32_bf16(a[rt], b, acc[rt][ct], 0, 0, 0);
    }
  }

  // ---- epilogue: relu(+bias)*snorm + residual -> Ho ----
  int oc = lane & 15;
  int orb = (lane >> 4) * 4;
#pragma unroll
  for (int rt = 0; rt < 2; rt++) {
#pragma unroll
    for (int ct = 0; ct < 4; ct++) {
      int col = col0 + ct * 16 + oc;
      float bv = bias[col];
#pragma unroll
      for (int r = 0; r < 4; r++) {
        int row = row0 + trow0 + rt * 16 + orb + r;
        float sn = snorm[row];
        float hres = __uint_as_float(((uint)Hb[(size_t)row * HD + col]) << 16);
        float o = fmaxf(acc[rt][ct][r] + bv, 0.f) * sn + hres;
        Ho[(size_t)row * HD + col] = f2b(o);
      }
    }
  }
}

// ---------------- readout ----------------
__global__ void k_wcombo(const float* __restrict__ W_ro, const float* __restrict__ W_pred,
                         float* __restrict__ wcv) {
  int i = threadIdx.x;  // 128
  float a = 0.f;
  for (int j = 0; j < HD; j++) a += W_ro[i * HD + j] * W_pred[j];
  wcv[i] = a;
}

__global__ void k_readout(const uint* __restrict__ H32, const float* __restrict__ wcv,
                          const int* __restrict__ gid, const float* __restrict__ inv_gcnt,
                          float* __restrict__ out) {
  int wave = threadIdx.x >> 6, lane = threadIdx.x & 63;
  int v = blockIdx.x * 4 + wave;
  uint x = H32[(size_t)v * 64 + lane];
  float2 wv = *(const float2*)(wcv + lane * 2);
  float p = blo(x) * wv.x + bhi(x) * wv.y;
#pragma unroll
  for (int o = 32; o > 0; o >>= 1) p += __shfl_down(p, o, 64);
  if (lane == 0) {
    int g = gid[v];
    atomicAdd(&out[g], p * inv_gcnt[g]);
  }
}

// ---------------- launch ----------------
extern "C" void kernel_launch(void* const* d_in, const int* in_sizes, int n_in,
                              void* d_out, int out_size, void* d_ws, size_t ws_size,
                              hipStream_t stream) {
  const float* h      = (const float*)d_in[0];
  const float* snorm  = (const float*)d_in[1];
  const float* W_emb  = (const float*)d_in[2];
  const float* W_node = (const float*)d_in[3];
  const float* b_node = (const float*)d_in[4];
  const float* W_ro   = (const float*)d_in[5];
  const float* W_pred = (const float*)d_in[6];
  const float* b_pred = (const float*)d_in[7];
  const int*   src    = (const int*)d_in[8];
  const int*   dst    = (const int*)d_in[9];
  const int*   gid    = (const int*)d_in[10];
  float* out = (float*)d_out;

  char* ws = (char*)d_ws;
  unsigned short* Xb   = (unsigned short*)(ws + OFF_XB);
  unsigned short* Yb   = (unsigned short*)(ws + OFF_YB);
  int*   esrc     = (int*)(ws + OFF_ESRC);
  int*   deg      = (int*)(ws + OFF_DEG);
  int*   gcnt     = (int*)(ws + OFF_GCNT);
  int*   row_s    = (int*)(ws + OFF_ROW);
  float* inv_deg  = (float*)(ws + OFF_IDEG);
  float* inv_gcnt = (float*)(ws + OFF_IGC);
  int*   bsum     = (int*)(ws + OFF_BSUM);
  int*   coff     = (int*)(ws + OFF_COFF);
  float* wcv      = (float*)(ws + OFF_WC);
  unsigned short* Wnt = (unsigned short*)(ws + OFF_WNT);
  uint*  ebuf     = (uint*)(ws + OFF_EBUF);
  int*   gcur     = (int*)(ws + OFF_GCUR);
  unsigned short* Wet = (unsigned short*)(ws + OFF_WET);

  hipMemsetAsync(ws + OFF_GCNT, 0, (size_t)NG * 4, stream);

  k_binit<<<1, NB, 0, stream>>>(gcur);
  k_bin<<<NE / 4096, 256, 0, stream>>>(src, dst, gcur, ebuf);
  k_deg<<<NB, 256, 0, stream>>>(gcur, ebuf, deg);
  k_scan1<<<NN / 1024, 256, 0, stream>>>(deg, bsum);
  k_scan2<<<1, 128, 0, stream>>>(bsum, coff);
  k_scan3<<<NN / 1024, 256, 0, stream>>>(deg, coff, row_s, inv_deg);
  k_place2<<<NB, 256, 0, stream>>>(gcur, ebuf, row_s, esrc);
  k_ghist<<<NN / 256, 256, 0, stream>>>(gid, gcnt);
  k_ginit<<<NG / 256, 256, 0, stream>>>(gcnt, inv_gcnt, out, b_pred);
  k_wprep<<<(NL * 256 * HD) / 256, 256, 0, stream>>>(W_node, Wnt);
  k_weprep<<<(HD * 32) / 256, 256, 0, stream>>>(W_emb, Wet);

  k_embed<<<NN / 64, 256, 0, stream>>>(h, Wet, Xb);

  for (int l = 0; l < NL; l++) {
    unsigned short* hb = (l & 1) ? Yb : Xb;
    unsigned short* ho = (l & 1) ? Xb : Yb;
    k_layer<<<NN / 64, 256, 0, stream>>>(hb, ho, row_s, deg, esrc, inv_deg,
                                         Wnt + (size_t)l * HD * 256,
                                         b_node + (size_t)l * HD, snorm);
  }
  // final h is in Xb after 4 layers

  k_wcombo<<<1, 128, 0, stream>>>(W_ro, W_pred, wcv);
  k_readout<<<NN / 4, 256, 0, stream>>>((const uint*)Xb, wcv, gid, inv_gcnt, out);
}